// Round 21
// baseline (104.103 us; speedup 1.0000x reference)
//
#include <hip/hip_runtime.h>
#include <hip/hip_bf16.h>

typedef __bf16 bf16x8 __attribute__((ext_vector_type(8)));
typedef float  f32x4  __attribute__((ext_vector_type(4)));
typedef float  f32x16 __attribute__((ext_vector_type(16)));

#define NB 16
#define NC 32
#define NH 32
#define NW 2048
#define NK (NC*NH)   // 1024
#define LOG2E 1.4426950408889634f
#define KP 40        // LDS k-pitch (bf16): 80 B rows

static __device__ __forceinline__ unsigned int pk2(float a, float b) {
    union { __bf16 h[2]; unsigned int u; } z;
    z.h[0] = (__bf16)a; z.h[1] = (__bf16)b;
    return z.u;
}

// ---------------------------------------------------------------------------
// Kernel 0: weights -> bf16. wb layout [3][32][1024]; wq scaled by log2e.
// ---------------------------------------------------------------------------
__global__ __launch_bounds__(256) void wprep_kernel(
    const float* __restrict__ wq, const float* __restrict__ wk,
    const float* __restrict__ wv, __bf16* __restrict__ wb)
{
    const int i = blockIdx.x * 256 + threadIdx.x;        // 24576 float4 units
    const float* srcs[3] = { wq, wk, wv };
    float4 v = *(const float4*)(srcs[i >> 13] + (size_t)(i & 8191) * 4);
    const float sc = (i >> 13) == 0 ? LOG2E : 1.0f;
    union { __bf16 h[4]; unsigned long long u; } z;
    z.h[0] = (__bf16)(v.x * sc); z.h[1] = (__bf16)(v.y * sc);
    z.h[2] = (__bf16)(v.z * sc); z.h[3] = (__bf16)(v.w * sc);
    *(unsigned long long*)(wb + (size_t)i * 4) = z.u;
}

// ---------------------------------------------------------------------------
// Kernel 1 (v4, R14-exact): QKV projection, NO K-split. Block = 384 thr
// (6 waves); wave nt owns one 16-channel output over all k. Per 32k step
// 256 stager threads load coalesced float4 rows, cvt->bf16, transposed
// ds_write into [32w][40k]; A-frag = ds_read_b128. 5 KB LDS dbuf.
// ---------------------------------------------------------------------------
__global__ __launch_bounds__(384) void proj_kernel(
    const float* __restrict__ x, const __bf16* __restrict__ wb,
    const float* __restrict__ bq, const float* __restrict__ bk,
    const float* __restrict__ bv,
    __bf16* __restrict__ qT, __bf16* __restrict__ kT, __bf16* __restrict__ V)
{
    const int b    = blockIdx.x >> 6;
    const int wt   = blockIdx.x & 63;
    const int nt   = threadIdx.x >> 6;       // wave = output ntile 0..5
    const int lane = threadIdx.x & 63;
    const int g    = lane >> 4;
    const int lr   = lane & 15;
    const int w0   = wt * 32;

    __shared__ __bf16 tile[2][32][KP];       // 5 KB total

    const float* xb = x + (size_t)b * NK * NW;
    const int skr = threadIdx.x >> 3;
    const int swc = (threadIdx.x & 7) * 4;
    const bool stager = (threadIdx.x < 256);
    const float* xs = xb + w0 + swc;

    const __bf16* wrow = wb + (size_t)(nt >> 1) * 32768
                            + (size_t)((nt & 1) * 16 + lr) * NK;

    f32x4 acc0 = {0.f,0.f,0.f,0.f}, acc1 = {0.f,0.f,0.f,0.f};

    f32x4 xv;
    if (stager) {
        xv = *(const f32x4*)(xs + (size_t)skr * NW);
        __bf16* wp = &tile[0][swc][skr];
        wp[0*KP] = (__bf16)xv[0]; wp[1*KP] = (__bf16)xv[1];
        wp[2*KP] = (__bf16)xv[2]; wp[3*KP] = (__bf16)xv[3];
    }
    bf16x8 Bcur = *(const bf16x8*)(wrow + g*8);
    __syncthreads();

    #pragma unroll
    for (int s = 0; s < 32; ++s) {
        const int cur = s & 1;
        f32x4 xn;
        if (s < 31 && stager)
            xn = *(const f32x4*)(xs + (size_t)((s+1)*32 + skr) * NW);
        bf16x8 Bnext;
        if (s < 31)
            Bnext = *(const bf16x8*)(wrow + (s+1)*32 + g*8);

        const bf16x8 af0 = *(const bf16x8*)&tile[cur][lr][g*8];
        const bf16x8 af1 = *(const bf16x8*)&tile[cur][16 + lr][g*8];
        acc0 = __builtin_amdgcn_mfma_f32_16x16x32_bf16(af0, Bcur, acc0, 0, 0, 0);
        acc1 = __builtin_amdgcn_mfma_f32_16x16x32_bf16(af1, Bcur, acc1, 0, 0, 0);

        if (s < 31 && stager) {
            __bf16* wp = &tile[cur ^ 1][swc][skr];
            wp[0*KP] = (__bf16)xn[0]; wp[1*KP] = (__bf16)xn[1];
            wp[2*KP] = (__bf16)xn[2]; wp[3*KP] = (__bf16)xn[3];
        }
        Bcur = Bnext;
        __syncthreads();
    }

    const int pid = nt >> 1;                 // 0=q,1=k,2=v
    const int o   = (nt & 1) * 16 + lr;
    const float* biases[3] = { bq, bk, bv };
    float bb = biases[pid][o];
    if (pid == 0) bb *= LOG2E;

    if (pid < 2) {
        __bf16* dst = (pid ? kT : qT) + (size_t)b * NW * NC;
        #pragma unroll
        for (int r = 0; r < 4; ++r) {
            dst[(size_t)(w0 +      g*4 + r) * NC + o] = (__bf16)(acc0[r] + bb);
            dst[(size_t)(w0 + 16 + g*4 + r) * NC + o] = (__bf16)(acc1[r] + bb);
        }
    } else {
        __bf16* dst = V + ((size_t)b * NC + o) * NW + w0;
        union { __bf16 h[4]; unsigned long long u; } z0, z1;
        #pragma unroll
        for (int r = 0; r < 4; ++r) {
            z0.h[r] = (__bf16)(acc0[r] + bb);
            z1.h[r] = (__bf16)(acc1[r] + bb);
        }
        *(unsigned long long*)(dst +      g*4) = z0.u;
        *(unsigned long long*)(dst + 16 + g*4) = z1.u;
    }
}

// ---------------------------------------------------------------------------
// Kernel 2: attention CORE only (R14 attn minus the fused epilogue).
// Writes compact O[b][c][w] fp32 (4 MB) at the merge stage; the h-broadcast
// residual add moves to the row-linear epi_kernel.
// ---------------------------------------------------------------------------
__global__ __launch_bounds__(256) void attn_kernel(
    const __bf16* __restrict__ qT, const __bf16* __restrict__ kT,
    const __bf16* __restrict__ V,
    float* __restrict__ O)
{
    const int b    = blockIdx.x >> 6;
    const int wt   = blockIdx.x & 63;
    const int w0   = wt * 32;
    const int wave = threadIdx.x >> 6;        // KV slice 0..3
    const int lane = threadIdx.x & 63;
    const int wl = lane & 31, hi = lane >> 5;
    const int swl = (wl & 0x13) | ((wl & 4) << 1) | ((wl & 8) >> 1);

    const __bf16* qTb = qT + (size_t)b * NW * NC;
    const __bf16* kTb = kT + (size_t)b * NW * NC;
    const __bf16* Vb  = V  + (size_t)b * NC * NW;

    const __bf16* qrow = qTb + (size_t)(w0 + wl) * NC;
    const bf16x8 qf0 = *(const bf16x8*)(qrow + hi*8);
    const bf16x8 qf1 = *(const bf16x8*)(qrow + 16 + hi*8);

    f32x16 acc, z16;
    #pragma unroll
    for (int r = 0; r < 16; ++r) { acc[r] = 0.f; z16[r] = 0.f; }
    float lsum = 0.f;

    const int vbeg = wave * 512;
    const __bf16* kbase = kTb + (size_t)swl * NC;
    const __bf16* vbase = Vb + (size_t)wl * NW;

#define KLD0(V0) (*(const bf16x8*)(kbase + (size_t)(V0) * NC + hi*8))
#define KLD1(V0) (*(const bf16x8*)(kbase + (size_t)(V0) * NC + 16 + hi*8))
#define VLD0(V0) (*(const bf16x8*)(vbase + (V0) + hi*8))
#define VLD1(V0) (*(const bf16x8*)(vbase + (V0) + 16 + hi*8))

    bf16x8 k0r = KLD0(vbeg), k1r = KLD1(vbeg);
    f32x16 s_cur = __builtin_amdgcn_mfma_f32_32x32x16_bf16(k0r, qf0, z16, 0, 0, 0);
    s_cur = __builtin_amdgcn_mfma_f32_32x32x16_bf16(k1r, qf1, s_cur, 0, 0, 0);
    k0r = KLD0(vbeg + 32); k1r = KLD1(vbeg + 32);
    bf16x8 v0r = VLD0(vbeg), v1r = VLD1(vbeg);

    #pragma unroll
    for (int it = 0; it < 16; ++it) {
        f32x16 s_next;
        if (it < 15) {
            s_next = __builtin_amdgcn_mfma_f32_32x32x16_bf16(k0r, qf0, z16, 0, 0, 0);
            s_next = __builtin_amdgcn_mfma_f32_32x32x16_bf16(k1r, qf1, s_next, 0, 0, 0);
        }
        if (it < 14) {
            const int vn = vbeg + (it + 2) * 32;
            k0r = KLD0(vn); k1r = KLD1(vn);
        }

        float p[16];
        #pragma unroll
        for (int r = 0; r < 16; ++r) p[r] = __builtin_amdgcn_exp2f(s_cur[r]);
        float ts[8];
        #pragma unroll
        for (int r = 0; r < 8; ++r) ts[r] = p[r] + p[r+8];
        #pragma unroll
        for (int r = 0; r < 4; ++r) ts[r] += ts[r+4];
        lsum += (ts[0] + ts[1]) + (ts[2] + ts[3]);

        union { unsigned int u[4]; bf16x8 v; } pfa, pfb;
        #pragma unroll
        for (int i = 0; i < 4; ++i) pfa.u[i] = pk2(p[2*i],     p[2*i + 1]);
        #pragma unroll
        for (int i = 0; i < 4; ++i) pfb.u[i] = pk2(p[8 + 2*i], p[8 + 2*i + 1]);

        acc = __builtin_amdgcn_mfma_f32_32x32x16_bf16(v0r, pfa.v, acc, 0, 0, 0);
        acc = __builtin_amdgcn_mfma_f32_32x32x16_bf16(v1r, pfb.v, acc, 0, 0, 0);

        if (it < 15) {
            const int vn = vbeg + (it + 1) * 32;
            v0r = VLD0(vn); v1r = VLD1(vn);
            s_cur = s_next;
        }
    }
#undef KLD0
#undef KLD1
#undef VLD0
#undef VLD1
    lsum += __shfl_xor(lsum, 32);

    __shared__ float sl[4][32];
    __shared__ float sO[4][32][33];

    if (hi == 0) sl[wave][wl] = lsum;
    #pragma unroll
    for (int r = 0; r < 16; ++r) {
        const int c = (r & 3) + 8*(r >> 2) + 4*hi;
        sO[wave][c][wl] = acc[r];
    }
    __syncthreads();

    {
        const int w  = threadIdx.x & 31;
        const int cg = threadIdx.x >> 5;          // 0..7 -> 4 c's each
        const float L = (sl[0][w] + sl[1][w]) + (sl[2][w] + sl[3][w]);
        const float rL = 1.0f / L;
        #pragma unroll
        for (int cc = 0; cc < 4; ++cc) {
            const int c = cg * 4 + cc;
            const float o = ((sO[0][c][w] + sO[1][c][w]) +
                             (sO[2][c][w] + sO[3][c][w]));
            O[((size_t)b * NC + c) * NW + w0 + w] = o * rL;
        }
    }
}

// ---------------------------------------------------------------------------
// Kernel 3: row-linear epilogue. Block = (b, c, w-half); each thread keeps
// its O float4 in a register and streams 32 h-rows: out = O + x, fully
// contiguous 1 KB per wave-instr loads/stores (the fused version did 128B
// windows at 8KB stride -- the ~2.2 TB/s pattern). NT out stores.
// ---------------------------------------------------------------------------
__global__ __launch_bounds__(256) void epi_kernel(
    const float* __restrict__ x, const float* __restrict__ O,
    float* __restrict__ out)
{
    const int b    = blockIdx.x >> 6;
    const int c    = (blockIdx.x >> 1) & 31;
    const int half = blockIdx.x & 1;
    const int w0   = half * 1024 + threadIdx.x * 4;

    const f32x4 o4 = *(const f32x4*)(O + ((size_t)b * NC + c) * NW + w0);
    const float* xp = x   + (((size_t)b * NC + c) * NH) * NW + w0;
    float*       op = out + (((size_t)b * NC + c) * NH) * NW + w0;

    #pragma unroll 8
    for (int h = 0; h < NH; ++h) {
        const size_t off = (size_t)h * NW;
        const f32x4 xv = *(const f32x4*)(xp + off);
        f32x4 ov;
        ov[0] = o4[0] + xv[0];
        ov[1] = o4[1] + xv[1];
        ov[2] = o4[2] + xv[2];
        ov[3] = o4[3] + xv[3];
        __builtin_nontemporal_store(ov, (f32x4*)(op + off));
    }
}

extern "C" void kernel_launch(void* const* d_in, const int* in_sizes, int n_in,
                              void* d_out, int out_size, void* d_ws, size_t ws_size,
                              hipStream_t stream)
{
    const float* x  = (const float*)d_in[0];
    const float* wq = (const float*)d_in[1];
    const float* bq = (const float*)d_in[2];
    const float* wk = (const float*)d_in[3];
    const float* bk = (const float*)d_in[4];
    const float* wv = (const float*)d_in[5];
    const float* bv = (const float*)d_in[6];
    float* out = (float*)d_out;

    // ws layout: qT@0 (2MB), kT@2MB, V@4MB, wb@6MB, O(fp32 4MB)@8MB
    char* ws = (char*)d_ws;
    __bf16* qT = (__bf16*)(ws);
    __bf16* kT = (__bf16*)(ws + (2u << 20));
    __bf16* V  = (__bf16*)(ws + (4u << 20));
    __bf16* wb = (__bf16*)(ws + (6u << 20));
    float*  O  = (float*)(ws + (8u << 20));

    hipLaunchKernelGGL(wprep_kernel, dim3(96), dim3(256), 0, stream, wq, wk, wv, wb);
    hipLaunchKernelGGL(proj_kernel, dim3(NB * 64), dim3(384), 0, stream,
                       x, wb, bq, bk, bv, qT, kT, V);
    hipLaunchKernelGGL(attn_kernel, dim3(NB * 64), dim3(256), 0, stream,
                       qT, kT, V, O);
    hipLaunchKernelGGL(epi_kernel, dim3(NB * 64), dim3(256), 0, stream,
                       x, O, out);
}

// Round 22
// 94.116 us; speedup vs baseline: 1.1061x; 1.1061x over previous
//
#include <hip/hip_runtime.h>
#include <hip/hip_bf16.h>

typedef __bf16 bf16x8 __attribute__((ext_vector_type(8)));
typedef float  f32x4  __attribute__((ext_vector_type(4)));
typedef float  f32x16 __attribute__((ext_vector_type(16)));

#define NB 16
#define NC 32
#define NH 32
#define NW 2048
#define NK (NC*NH)   // 1024
#define LOG2E 1.4426950408889634f
#define KP 40        // LDS k-pitch (bf16): 80 B rows

static __device__ __forceinline__ unsigned int pk2(float a, float b) {
    union { __bf16 h[2]; unsigned int u; } z;
    z.h[0] = (__bf16)a; z.h[1] = (__bf16)b;
    return z.u;
}

// ---------------------------------------------------------------------------
// Kernel 0: weights -> bf16. wb layout [3][32][1024]; wq scaled by log2e.
// ---------------------------------------------------------------------------
__global__ __launch_bounds__(256) void wprep_kernel(
    const float* __restrict__ wq, const float* __restrict__ wk,
    const float* __restrict__ wv, __bf16* __restrict__ wb)
{
    const int i = blockIdx.x * 256 + threadIdx.x;        // 24576 float4 units
    const float* srcs[3] = { wq, wk, wv };
    float4 v = *(const float4*)(srcs[i >> 13] + (size_t)(i & 8191) * 4);
    const float sc = (i >> 13) == 0 ? LOG2E : 1.0f;
    union { __bf16 h[4]; unsigned long long u; } z;
    z.h[0] = (__bf16)(v.x * sc); z.h[1] = (__bf16)(v.y * sc);
    z.h[2] = (__bf16)(v.z * sc); z.h[3] = (__bf16)(v.w * sc);
    *(unsigned long long*)(wb + (size_t)i * 4) = z.u;
}

// ---------------------------------------------------------------------------
// Kernel 1 (v4, R14-exact): QKV projection, NO K-split.
// Block = 384 thr (6 waves) covers 32 w; wave nt owns ONE 16-channel output
// tile over all 1024 k. Per 32k step 256 stager threads do coalesced float4
// row loads, cvt->bf16, transposed ds_write into [32w][40k]; A-frag =
// ds_read_b128; B-frags reg-double-buffered from bf16 wb (L2-hot).
// LDS 5 KB (2 x 2.5 KB dbuf). Grid = 1024 blocks.
// ---------------------------------------------------------------------------
__global__ __launch_bounds__(384) void proj_kernel(
    const float* __restrict__ x, const __bf16* __restrict__ wb,
    const float* __restrict__ bq, const float* __restrict__ bk,
    const float* __restrict__ bv,
    __bf16* __restrict__ qT, __bf16* __restrict__ kT, __bf16* __restrict__ V)
{
    const int b    = blockIdx.x >> 6;
    const int wt   = blockIdx.x & 63;
    const int nt   = threadIdx.x >> 6;       // wave = output ntile 0..5
    const int lane = threadIdx.x & 63;
    const int g    = lane >> 4;
    const int lr   = lane & 15;
    const int w0   = wt * 32;

    __shared__ __bf16 tile[2][32][KP];       // [buf][w][k], 5 KB total

    const float* xb = x + (size_t)b * NK * NW;

    const int skr = threadIdx.x >> 3;
    const int swc = (threadIdx.x & 7) * 4;
    const bool stager = (threadIdx.x < 256);
    const float* xs = xb + w0 + swc;

    const __bf16* wrow = wb + (size_t)(nt >> 1) * 32768
                            + (size_t)((nt & 1) * 16 + lr) * NK;

    f32x4 acc0 = {0.f,0.f,0.f,0.f}, acc1 = {0.f,0.f,0.f,0.f};

    f32x4 xv;
    if (stager) {
        xv = *(const f32x4*)(xs + (size_t)skr * NW);
        __bf16* wp = &tile[0][swc][skr];
        wp[0*KP] = (__bf16)xv[0]; wp[1*KP] = (__bf16)xv[1];
        wp[2*KP] = (__bf16)xv[2]; wp[3*KP] = (__bf16)xv[3];
    }
    bf16x8 Bcur = *(const bf16x8*)(wrow + g*8);
    __syncthreads();

    #pragma unroll
    for (int s = 0; s < 32; ++s) {
        const int cur = s & 1;
        f32x4 xn;
        if (s < 31 && stager)
            xn = *(const f32x4*)(xs + (size_t)((s+1)*32 + skr) * NW);
        bf16x8 Bnext;
        if (s < 31)
            Bnext = *(const bf16x8*)(wrow + (s+1)*32 + g*8);

        const bf16x8 af0 = *(const bf16x8*)&tile[cur][lr][g*8];
        const bf16x8 af1 = *(const bf16x8*)&tile[cur][16 + lr][g*8];
        acc0 = __builtin_amdgcn_mfma_f32_16x16x32_bf16(af0, Bcur, acc0, 0, 0, 0);
        acc1 = __builtin_amdgcn_mfma_f32_16x16x32_bf16(af1, Bcur, acc1, 0, 0, 0);

        if (s < 31 && stager) {
            __bf16* wp = &tile[cur ^ 1][swc][skr];
            wp[0*KP] = (__bf16)xn[0]; wp[1*KP] = (__bf16)xn[1];
            wp[2*KP] = (__bf16)xn[2]; wp[3*KP] = (__bf16)xn[3];
        }
        Bcur = Bnext;
        __syncthreads();
    }

    const int pid = nt >> 1;                 // 0=q,1=k,2=v
    const int o   = (nt & 1) * 16 + lr;
    const float* biases[3] = { bq, bk, bv };
    float bb = biases[pid][o];
    if (pid == 0) bb *= LOG2E;

    if (pid < 2) {
        __bf16* dst = (pid ? kT : qT) + (size_t)b * NW * NC;
        #pragma unroll
        for (int r = 0; r < 4; ++r) {
            dst[(size_t)(w0 +      g*4 + r) * NC + o] = (__bf16)(acc0[r] + bb);
            dst[(size_t)(w0 + 16 + g*4 + r) * NC + o] = (__bf16)(acc1[r] + bb);
        }
    } else {
        __bf16* dst = V + ((size_t)b * NC + o) * NW + w0;
        union { __bf16 h[4]; unsigned long long u; } z0, z1;
        #pragma unroll
        for (int r = 0; r < 4; ++r) {
            z0.h[r] = (__bf16)(acc0[r] + bb);
            z1.h[r] = (__bf16)(acc1[r] + bb);
        }
        *(unsigned long long*)(dst +      g*4) = z0.u;
        *(unsigned long long*)(dst + 16 + g*4) = z1.u;
    }
}

// ---------------------------------------------------------------------------
// Kernel 2: flash attention (R10/R14, verified; at its HBM stream floor):
// fixed-max softmax (M=0), sigma-permuted K rows (lane-local PV fragments),
// software-pipelined loop, exp2 via __builtin_amdgcn_exp2f, fused
// h-broadcast residual epilogue with NT out stores.
// ---------------------------------------------------------------------------
__global__ __launch_bounds__(256) void attn_kernel(
    const float* __restrict__ x,
    const __bf16* __restrict__ qT, const __bf16* __restrict__ kT,
    const __bf16* __restrict__ V,
    float* __restrict__ out)
{
    const int b    = blockIdx.x >> 6;
    const int wt   = blockIdx.x & 63;
    const int w0   = wt * 32;
    const int wave = threadIdx.x >> 6;        // KV slice 0..3
    const int lane = threadIdx.x & 63;
    const int wl = lane & 31, hi = lane >> 5;
    const int swl = (wl & 0x13) | ((wl & 4) << 1) | ((wl & 8) >> 1);

    const __bf16* qTb = qT + (size_t)b * NW * NC;
    const __bf16* kTb = kT + (size_t)b * NW * NC;
    const __bf16* Vb  = V  + (size_t)b * NC * NW;

    const __bf16* qrow = qTb + (size_t)(w0 + wl) * NC;
    const bf16x8 qf0 = *(const bf16x8*)(qrow + hi*8);
    const bf16x8 qf1 = *(const bf16x8*)(qrow + 16 + hi*8);

    f32x16 acc, z16;
    #pragma unroll
    for (int r = 0; r < 16; ++r) { acc[r] = 0.f; z16[r] = 0.f; }
    float lsum = 0.f;

    const int vbeg = wave * 512;
    const __bf16* kbase = kTb + (size_t)swl * NC;
    const __bf16* vbase = Vb + (size_t)wl * NW;

#define KLD0(V0) (*(const bf16x8*)(kbase + (size_t)(V0) * NC + hi*8))
#define KLD1(V0) (*(const bf16x8*)(kbase + (size_t)(V0) * NC + 16 + hi*8))
#define VLD0(V0) (*(const bf16x8*)(vbase + (V0) + hi*8))
#define VLD1(V0) (*(const bf16x8*)(vbase + (V0) + 16 + hi*8))

    bf16x8 k0r = KLD0(vbeg), k1r = KLD1(vbeg);
    f32x16 s_cur = __builtin_amdgcn_mfma_f32_32x32x16_bf16(k0r, qf0, z16, 0, 0, 0);
    s_cur = __builtin_amdgcn_mfma_f32_32x32x16_bf16(k1r, qf1, s_cur, 0, 0, 0);
    k0r = KLD0(vbeg + 32); k1r = KLD1(vbeg + 32);
    bf16x8 v0r = VLD0(vbeg), v1r = VLD1(vbeg);

    #pragma unroll
    for (int it = 0; it < 16; ++it) {
        f32x16 s_next;
        if (it < 15) {
            s_next = __builtin_amdgcn_mfma_f32_32x32x16_bf16(k0r, qf0, z16, 0, 0, 0);
            s_next = __builtin_amdgcn_mfma_f32_32x32x16_bf16(k1r, qf1, s_next, 0, 0, 0);
        }
        if (it < 14) {
            const int vn = vbeg + (it + 2) * 32;
            k0r = KLD0(vn); k1r = KLD1(vn);
        }

        float p[16];
        #pragma unroll
        for (int r = 0; r < 16; ++r) p[r] = __builtin_amdgcn_exp2f(s_cur[r]);
        float ts[8];
        #pragma unroll
        for (int r = 0; r < 8; ++r) ts[r] = p[r] + p[r+8];
        #pragma unroll
        for (int r = 0; r < 4; ++r) ts[r] += ts[r+4];
        lsum += (ts[0] + ts[1]) + (ts[2] + ts[3]);

        union { unsigned int u[4]; bf16x8 v; } pfa, pfb;
        #pragma unroll
        for (int i = 0; i < 4; ++i) pfa.u[i] = pk2(p[2*i],     p[2*i + 1]);
        #pragma unroll
        for (int i = 0; i < 4; ++i) pfb.u[i] = pk2(p[8 + 2*i], p[8 + 2*i + 1]);

        acc = __builtin_amdgcn_mfma_f32_32x32x16_bf16(v0r, pfa.v, acc, 0, 0, 0);
        acc = __builtin_amdgcn_mfma_f32_32x32x16_bf16(v1r, pfb.v, acc, 0, 0, 0);

        if (it < 15) {
            const int vn = vbeg + (it + 1) * 32;
            v0r = VLD0(vn); v1r = VLD1(vn);
            s_cur = s_next;
        }
    }
#undef KLD0
#undef KLD1
#undef VLD0
#undef VLD1
    lsum += __shfl_xor(lsum, 32);

    __shared__ float sl[4][32];
    __shared__ float sO[4][32][33];
    __shared__ float Of[32][33];

    if (hi == 0) sl[wave][wl] = lsum;
    #pragma unroll
    for (int r = 0; r < 16; ++r) {
        const int c = (r & 3) + 8*(r >> 2) + 4*hi;
        sO[wave][c][wl] = acc[r];
    }
    __syncthreads();

    {
        const int w  = threadIdx.x & 31;
        const int cg = threadIdx.x >> 5;
        const float L = (sl[0][w] + sl[1][w]) + (sl[2][w] + sl[3][w]);
        const float rL = 1.0f / L;
        #pragma unroll
        for (int cc = 0; cc < 4; ++cc) {
            const int c = cg * 4 + cc;
            const float o = ((sO[0][c][w] + sO[1][c][w]) +
                             (sO[2][c][w] + sO[3][c][w]));
            Of[c][w] = o * rL;
        }
    }
    __syncthreads();

    const float* xb = x   + (size_t)b * NC * NH * NW + w0;
    float*       ob = out + (size_t)b * NC * NH * NW + w0;
    const int chunk = threadIdx.x & 7;
    #pragma unroll
    for (int it = 0; it < 32; ++it) {
        const int row = it*32 + (threadIdx.x >> 3);
        const int c = row >> 5, h = row & 31;
        const size_t off = ((size_t)c * NH + h) * NW + chunk*4;
        const f32x4 xv = *(const f32x4*)(xb + off);
        f32x4 ov;
        ov[0] = Of[c][chunk*4 + 0] + xv[0];
        ov[1] = Of[c][chunk*4 + 1] + xv[1];
        ov[2] = Of[c][chunk*4 + 2] + xv[2];
        ov[3] = Of[c][chunk*4 + 3] + xv[3];
        __builtin_nontemporal_store(ov, (f32x4*)(ob + off));
    }
}

extern "C" void kernel_launch(void* const* d_in, const int* in_sizes, int n_in,
                              void* d_out, int out_size, void* d_ws, size_t ws_size,
                              hipStream_t stream)
{
    const float* x  = (const float*)d_in[0];
    const float* wq = (const float*)d_in[1];
    const float* bq = (const float*)d_in[2];
    const float* wk = (const float*)d_in[3];
    const float* bk = (const float*)d_in[4];
    const float* wv = (const float*)d_in[5];
    const float* bv = (const float*)d_in[6];
    float* out = (float*)d_out;

    // ws layout (bf16): qT [B][W][32] @0, kT @2MB, V [B][32][W] @4MB, wb @6MB
    char* ws = (char*)d_ws;
    __bf16* qT = (__bf16*)(ws);
    __bf16* kT = (__bf16*)(ws + (2u << 20));
    __bf16* V  = (__bf16*)(ws + (4u << 20));
    __bf16* wb = (__bf16*)(ws + (6u << 20));

    hipLaunchKernelGGL(wprep_kernel, dim3(96), dim3(256), 0, stream, wq, wk, wv, wb);
    hipLaunchKernelGGL(proj_kernel, dim3(NB * 64), dim3(384), 0, stream,
                       x, wb, bq, bk, bv, qT, kT, V);
    hipLaunchKernelGGL(attn_kernel, dim3(NB * 64), dim3(256), 0, stream,
                       x, qT, kT, V, out);
}